// Round 3
// baseline (252.126 us; speedup 1.0000x reference)
//
#include <hip/hip_runtime.h>
#include <cstdint>
#include <cstddef>

// LSTM cell: B=16384, IN=HID=512.
// R9 resubmit (R2 bench was an infra failure: container acquire died; no
// kernel verdict). 256x256/BK=64/4-phase counted-vmcnt(6) pipeline, ONE
// barrier per phase: [loads, stage, lgkmcnt(0), (vmcnt@ph3), s_barrier,
// sched_barrier, MFMA]. lgkm0 BEFORE the barrier makes barrier-exit imply
// "all waves' ds_reads drained" -> the overwriting stage in the next phase
// is WAR-safe with a single barrier. Waves leaving MFMA early issue the
// next phase's ds_reads while others still compute -> LDS drain overlaps
// the MFMA window (R8 serialized them; MfmaUtil stuck at 29%).
// Region pipeline identical to R8 (verified):
//   ph0: read Akc0+Bkc0(t); stage Akc1(t+1)->buf[nxt]  (freed t-1.ph3 BAR)
//   ph1: read Akc0(t) h1 ;  stage Bkc0(t+2)->buf[cur]  (freed t.ph0 BAR)
//   ph2: read Akc1+Bkc1(t); stage Akc0(t+2)->buf[cur]  (freed t.ph1 BAR)
//   ph3: read Akc1(t) h1 ;  stage Bkc1(t+2)->buf[cur]  (freed t.ph2 BAR)
//   vmcnt(6) at ph3 = 3 newest regions may fly; tile t+1 fully resident.

#define BATCH 16384
#define KDIM  1024
#define NPK   2048
#define HIDN  512

#define BM 256
#define BN 256
#define BK 64
#define NT (KDIM / BK)   // 16

typedef __bf16 bf16x8 __attribute__((ext_vector_type(8)));
typedef float  f32x4  __attribute__((ext_vector_type(4)));

__device__ __forceinline__ unsigned short f2bf(float f) {
  unsigned int u = __builtin_bit_cast(unsigned int, f);
  u += 0x7fffu + ((u >> 16) & 1u);   // RNE
  return (unsigned short)(u >> 16);
}

__device__ __forceinline__ float fast_sigmoid(float x) {
  return __builtin_amdgcn_rcpf(1.0f + __expf(-x));
}
__device__ __forceinline__ float fast_tanh(float x) {
  return 1.0f - 2.0f * __builtin_amdgcn_rcpf(1.0f + __expf(2.0f * x));
}

// async global->LDS, 16 B per lane; LDS dest = wave-uniform base + lane*16
__device__ __forceinline__ void gload_lds16(const void* gp, void* lds_wave_base) {
  auto g = (const __attribute__((address_space(1))) unsigned int*)(unsigned long long)gp;
  auto l = (__attribute__((address_space(3))) unsigned int*)
           (unsigned int)(unsigned long long)lds_wave_base;
  __builtin_amdgcn_global_load_lds(g, l, 16, 0, 0);
}

// ---------------- prep kernels (unchanged) ----------------
__global__ __launch_bounds__(256) void pack_a(const float* __restrict__ x,
                                              const float* __restrict__ h,
                                              unsigned short* __restrict__ A) {
  int c = blockIdx.x * 256 + threadIdx.x;   // chunk of 8 elements
  int idx = c << 3;
  int b = idx >> 10;          // row
  int k = idx & 1023;         // col
  const float* src = (k < 512) ? (x + (size_t)b * 512 + k)
                               : (h + (size_t)b * 512 + (k - 512));
  float4 lo = ((const float4*)src)[0];
  float4 hi = ((const float4*)src)[1];
  union { unsigned short s[8]; uint4 u; } o;
  o.s[0]=f2bf(lo.x); o.s[1]=f2bf(lo.y); o.s[2]=f2bf(lo.z); o.s[3]=f2bf(lo.w);
  o.s[4]=f2bf(hi.x); o.s[5]=f2bf(hi.y); o.s[6]=f2bf(hi.z); o.s[7]=f2bf(hi.w);
  ((uint4*)A)[c] = o.u;
}

struct GatePtrs {
  const float* wx[4];  // gate order: i, g, f, o
  const float* wh[4];
  const float* bx[4];
  const float* bh[4];
};

// W row-major bf16 [2048][1024], rows packed r = b*128 + wn*64 + gate*16 + jl,
// j = b*32 + wn*16 + jl.
__global__ __launch_bounds__(256) void pack_w(GatePtrs P,
                                              unsigned short* __restrict__ W,
                                              float* __restrict__ bias) {
  int c = blockIdx.x * 256 + threadIdx.x;   // chunk of 8, 128 chunks per row
  int r = c >> 7;
  int k = (c & 127) << 3;
  int b    = r >> 7;
  int rem  = r & 127;
  int wn   = (rem >> 6) & 1;
  int gate = (rem >> 4) & 3;
  int jl   = rem & 15;
  int j = b * 32 + wn * 16 + jl;
  const float* src = (k < 512) ? (P.wx[gate] + (size_t)j * 512 + k)
                               : (P.wh[gate] + (size_t)j * 512 + (k - 512));
  float4 lo = ((const float4*)src)[0];
  float4 hi = ((const float4*)src)[1];
  union { unsigned short s[8]; uint4 u; } o;
  o.s[0]=f2bf(lo.x); o.s[1]=f2bf(lo.y); o.s[2]=f2bf(lo.z); o.s[3]=f2bf(lo.w);
  o.s[4]=f2bf(hi.x); o.s[5]=f2bf(hi.y); o.s[6]=f2bf(hi.z); o.s[7]=f2bf(hi.w);
  ((uint4*)W)[c] = o.u;
  if ((c & 127) == 0) bias[r] = P.bx[gate][j] + P.bh[gate][j];
}

// ---------------- fused GEMM + LSTM epilogue ----------------

__global__ __launch_bounds__(512, 2) void lstm_gemm(
    const unsigned short* __restrict__ A,    // [16384,1024] bf16 row-major
    const unsigned short* __restrict__ W,    // [2048,1024] bf16 packed rows
    const float* __restrict__ bias,          // [2048] packed
    const float* __restrict__ Cin,           // [16384,512]
    float* __restrict__ Hout,                // [16384,512]
    float* __restrict__ Cout) {              // [16384,512]
  // 2 buffers x { Akc0, Akc1, Bkc0, Bkc1 } regions, each [256 rows][32 cols]
  // bf16 = 8192 ushorts = 16 KB. Total 128 KB -> 1 block/CU.
  __shared__ __align__(16) unsigned short lds[2 * 32768];

  const int tid  = threadIdx.x;
  const int lane = tid & 63;
  const int wv   = tid >> 6;     // 0..7
  const int wm   = wv >> 2;      // 0..1 (wave row; 2 x 128 = 256)
  const int wn   = wv & 3;       // 0..3 (wave col; 4 x 64  = 256)

  // XCD-aware swizzle: 512 blocks, nwg%8==0 -> simple swizzle bijective.
  const int lin = blockIdx.x;    // 0..511
  const int xcd = lin & 7;
  const int idx = lin >> 3;
  const int bn  = idx & 7;       // 0..7
  const int bm  = (idx >> 3) * 8 + xcd;  // 0..63

  // ---- staging addressing: one region = 2 gload_lds16 per thread ----
  const int srow = lane >> 2;            // 0..15
  const int scol = (lane & 3) << 3;      // 0,8,16,24
  const unsigned short* gA = A + (size_t)(bm * 256 + wv * 32 + srow) * KDIM + scol;
  const unsigned short* gB = W + (size_t)(bn * 256 + wv * 32 + srow) * KDIM + scol;
  const int lA = wv * 1024;              // wave's 32-row slab (ushorts) in a region

#define REG_A(b, c) ((b) * 32768 + (c) * 8192)
#define REG_B(b, c) ((b) * 32768 + 16384 + (c) * 8192)

#define STAGE_A(b, c, tt) do {                                      \
    const unsigned short* s_ = gA + (tt) * 64 + (c) * 32;           \
    gload_lds16(s_,            &lds[REG_A(b, c) + lA]);             \
    gload_lds16(s_ + 16 * KDIM, &lds[REG_A(b, c) + lA + 512]);      \
  } while (0)
#define STAGE_B(b, c, tt) do {                                      \
    const unsigned short* s_ = gB + (tt) * 64 + (c) * 32;           \
    gload_lds16(s_,            &lds[REG_B(b, c) + lA]);             \
    gload_lds16(s_ + 16 * KDIM, &lds[REG_B(b, c) + lA + 512]);      \
  } while (0)

  // ---- fragment addressing (contiguous 1024 B per 64-lane read) ----
  const int lrow = lane & 15;
  const int kg   = (lane >> 4) << 3;     // k-offset (ushorts) within 32-col chunk
  const int aoff = wm * 4096 + lrow * 32 + kg;   // + h*2048 + mi*512
  const int boff = wn * 2048 + lrow * 32 + kg;   // + ni*512

  f32x4 acc[8][4] = {};   // [m: h*4+mi][gate ni]
  bf16x8 af[4], bfr[4];

#define LOAD_AF(b, c, h) do {                                                  \
    _Pragma("unroll")                                                          \
    for (int mi = 0; mi < 4; ++mi)                                             \
      af[mi] = *reinterpret_cast<const bf16x8*>(                               \
          &lds[REG_A(b, c) + aoff + (h) * 2048 + mi * 512]);                   \
  } while (0)
#define LOAD_BF(b, c) do {                                                     \
    _Pragma("unroll")                                                          \
    for (int ni = 0; ni < 4; ++ni)                                             \
      bfr[ni] = *reinterpret_cast<const bf16x8*>(                              \
          &lds[REG_B(b, c) + boff + ni * 512]);                                \
  } while (0)
#define MFMA_BLK(h) do {                                                       \
    __builtin_amdgcn_s_setprio(1);                                             \
    _Pragma("unroll")                                                          \
    for (int mi = 0; mi < 4; ++mi)                                             \
      _Pragma("unroll")                                                        \
      for (int ni = 0; ni < 4; ++ni)                                           \
        acc[(h) * 4 + mi][ni] = __builtin_amdgcn_mfma_f32_16x16x32_bf16(       \
            af[mi], bfr[ni], acc[(h) * 4 + mi][ni], 0, 0, 0);                  \
    __builtin_amdgcn_s_setprio(0);                                             \
  } while (0)

#define BAR()  __builtin_amdgcn_s_barrier()
#define SCB()  __builtin_amdgcn_sched_barrier(0)
// drain own ds_reads BEFORE the barrier -> barrier-exit implies all waves'
// reads of the previous regions are complete (single-barrier WAR safety).
#define WAIT_LGKM0() asm volatile("s_waitcnt lgkmcnt(0)" ::: "memory")

  // ---- prologue: issue order defines vmcnt arithmetic ----
  // [Bkc0(0), Akc0(0), Bkc1(0), Akc1(0), Bkc0(1), Akc0(1), Bkc1(1)]
  STAGE_B(0, 0, 0); STAGE_A(0, 0, 0); STAGE_B(0, 1, 0); STAGE_A(0, 1, 0);
  STAGE_B(1, 0, 1); STAGE_A(1, 0, 1); STAGE_B(1, 1, 1);
  asm volatile("s_waitcnt vmcnt(6)" ::: "memory");
  BAR(); SCB();

#pragma unroll 2
  for (int t = 0; t < NT; ++t) {
    const int cur = t & 1;
    const int nxt = cur ^ 1;
    const int t1 = (t + 1 < NT) ? t + 1 : NT - 1;  // clamp: redundant re-stage,
    const int t2 = (t + 2 < NT) ? t + 2 : NT - 1;  // keeps vmcnt counts uniform
    // ---- ph0: kc0, m-half 0 ----
    LOAD_AF(cur, 0, 0); LOAD_BF(cur, 0);
    STAGE_A(nxt, 1, t1);           // buf[nxt].Akc1: last read t-1.ph3, BAR'd
    WAIT_LGKM0();
    BAR(); SCB();
    MFMA_BLK(0);
    // ---- ph1: kc0, m-half 1 (bfr reused from ph0) ----
    LOAD_AF(cur, 0, 1);
    STAGE_B(cur, 0, t2);           // overwrites Bkc0(cur): drained pre ph0-BAR
    WAIT_LGKM0();
    BAR(); SCB();
    MFMA_BLK(1);
    // ---- ph2: kc1, m-half 0 ----
    LOAD_AF(cur, 1, 0); LOAD_BF(cur, 1);
    STAGE_A(cur, 0, t2);           // overwrites Akc0(cur): drained pre ph1-BAR
    WAIT_LGKM0();
    BAR(); SCB();
    MFMA_BLK(0);
    // ---- ph3: kc1, m-half 1 ----
    LOAD_AF(cur, 1, 1);
    STAGE_B(cur, 1, t2);           // overwrites Bkc1(cur): drained pre ph2-BAR
    WAIT_LGKM0();
    // counted wait: newest 3 regions (tile t+2 partial) may stay in flight;
    // everything through Akc1(t+1) complete -> tile t+1 resident.
    asm volatile("s_waitcnt vmcnt(6)" ::: "memory");
    BAR(); SCB();
    MFMA_BLK(1);
  }
  asm volatile("s_waitcnt vmcnt(0)" ::: "memory");  // drain tail stages

  // ---- epilogue: ni == gate (0=i,1=g,2=f,3=o); lane's j fixed ----
  // W-packed row = bn*256 + wn*64 + ni*16 + jl decodes (pack_w layout) to
  // j = (bn*2 + (wn>>1))*32 + (wn&1)*16 + jl, gate = ni.
  const int jl = lane & 15;
  const int rq = (lane >> 4) << 2;
  const int j  = (bn * 2 + (wn >> 1)) * 32 + (wn & 1) * 16 + jl;
  float bv[4];
#pragma unroll
  for (int ni = 0; ni < 4; ++ni)
    bv[ni] = bias[bn * 256 + wn * 64 + ni * 16 + jl];

#pragma unroll
  for (int mi = 0; mi < 8; ++mi) {
    const int row0 = bm * 256 + wm * 128 + (mi >> 2) * 64 + (mi & 3) * 16 + rq;
#pragma unroll
    for (int r = 0; r < 4; ++r) {
      int row = row0 + r;
      float iv = fast_sigmoid(acc[mi][0][r] + bv[0]);
      float gv = fast_tanh   (acc[mi][1][r] + bv[1]);
      float fv = fast_sigmoid(acc[mi][2][r] + bv[2]);
      float ov = fast_sigmoid(acc[mi][3][r] + bv[3]);
      float cold = Cin[(size_t)row * HIDN + j];
      float cnew = fv * cold + iv * gv;
      Hout[(size_t)row * HIDN + j] = ov * fast_tanh(cnew);
      Cout[(size_t)row * HIDN + j] = cnew;
    }
  }
}

// ---------------- launch ----------------

extern "C" void kernel_launch(void* const* d_in, const int* in_sizes, int n_in,
                              void* d_out, int out_size, void* d_ws, size_t ws_size,
                              hipStream_t stream) {
  const float* x   = (const float*)d_in[0];
  const float* h   = (const float*)d_in[1];
  const float* c   = (const float*)d_in[2];
  const float* Wxi = (const float*)d_in[3];  const float* bxi = (const float*)d_in[4];
  const float* Wxo = (const float*)d_in[5];  const float* bxo = (const float*)d_in[6];
  const float* Wxf = (const float*)d_in[7];  const float* bxf = (const float*)d_in[8];
  const float* Wxg = (const float*)d_in[9];  const float* bxg = (const float*)d_in[10];
  const float* Whi = (const float*)d_in[11]; const float* bhi = (const float*)d_in[12];
  const float* Who = (const float*)d_in[13]; const float* bho = (const float*)d_in[14];
  const float* Whf = (const float*)d_in[15]; const float* bhf = (const float*)d_in[16];
  const float* Whg = (const float*)d_in[17]; const float* bhg = (const float*)d_in[18];

  char* ws = (char*)d_ws;
  unsigned short* Apack = (unsigned short*)ws;                              // 32 MB
  unsigned short* Wpack = (unsigned short*)(ws + (size_t)BATCH * KDIM * 2); // 4 MB
  float* biasp = (float*)(ws + (size_t)BATCH * KDIM * 2 + (size_t)NPK * KDIM * 2);

  pack_a<<<(BATCH * KDIM / 8) / 256, 256, 0, stream>>>(x, h, Apack);

  GatePtrs P;
  P.wx[0] = Wxi; P.wx[1] = Wxg; P.wx[2] = Wxf; P.wx[3] = Wxo;
  P.wh[0] = Whi; P.wh[1] = Whg; P.wh[2] = Whf; P.wh[3] = Who;
  P.bx[0] = bxi; P.bx[1] = bxg; P.bx[2] = bxf; P.bx[3] = bxo;
  P.bh[0] = bhi; P.bh[1] = bhg; P.bh[2] = bhf; P.bh[3] = bho;
  pack_w<<<(NPK * KDIM / 8) / 256, 256, 0, stream>>>(P, Wpack, biasp);

  float* Hout = (float*)d_out;
  float* Cout = Hout + (size_t)BATCH * HIDN;
  lstm_gemm<<<dim3((BATCH / BM) * (NPK / BN)), 512, 0, stream>>>(
      Apack, Wpack, biasp, c, Hout, Cout);
}

// Round 6
// 249.979 us; speedup vs baseline: 1.0086x; 1.0086x over previous
//
#include <hip/hip_runtime.h>
#include <cstdint>
#include <cstddef>

// LSTM cell: B=16384, IN=HID=512.
// R10 resubmit #2 (R4/R5 benches were GPU-acquisition timeouts; kernel has
// never run). R10 = R9 + T2 k-slot XOR swizzle. R7/R8/R9 all pinned at
// ~30% MfmaUtil with SQ_LDS_BANK_CONFLICT = 4.0 extra cyc per ds_read_b128:
// the fragment read (byte = lrow*64 + kslot*16) is an 8-WAY bank conflict
// per 16-lane group (even rows -> banks 0-3, odd -> 16-19). Fix: involution
// swizzle c(row) = (row>>1)&3 on the four 16-B k-slots of each 64-B row:
//  - write side: gload_lds stays LINEAR; global source column pre-swizzled
//    (lane fetches chunk (lane&3)^c(srow))  [rule #21 / m173]
//  - read side: kg = ((lane>>4) ^ c(lrow)) << 3; contents cancel, each lane
//    still receives its MFMA-required k-chunk.
// Post-swizzle: 2 lanes/bank per 16-lane group = conflict-free (m136).
// Schedule unchanged from R9 (4-phase, counted vmcnt(6), 1 barrier/phase).

#define BATCH 16384
#define KDIM  1024
#define NPK   2048
#define HIDN  512

#define BM 256
#define BN 256
#define BK 64
#define NT (KDIM / BK)   // 16

typedef __bf16 bf16x8 __attribute__((ext_vector_type(8)));
typedef float  f32x4  __attribute__((ext_vector_type(4)));

__device__ __forceinline__ unsigned short f2bf(float f) {
  unsigned int u = __builtin_bit_cast(unsigned int, f);
  u += 0x7fffu + ((u >> 16) & 1u);   // RNE
  return (unsigned short)(u >> 16);
}

__device__ __forceinline__ float fast_sigmoid(float x) {
  return __builtin_amdgcn_rcpf(1.0f + __expf(-x));
}
__device__ __forceinline__ float fast_tanh(float x) {
  return 1.0f - 2.0f * __builtin_amdgcn_rcpf(1.0f + __expf(2.0f * x));
}

// async global->LDS, 16 B per lane; LDS dest = wave-uniform base + lane*16
__device__ __forceinline__ void gload_lds16(const void* gp, void* lds_wave_base) {
  auto g = (const __attribute__((address_space(1))) unsigned int*)(unsigned long long)gp;
  auto l = (__attribute__((address_space(3))) unsigned int*)
           (unsigned int)(unsigned long long)lds_wave_base;
  __builtin_amdgcn_global_load_lds(g, l, 16, 0, 0);
}

// ---------------- prep kernels (unchanged) ----------------
__global__ __launch_bounds__(256) void pack_a(const float* __restrict__ x,
                                              const float* __restrict__ h,
                                              unsigned short* __restrict__ A) {
  int c = blockIdx.x * 256 + threadIdx.x;   // chunk of 8 elements
  int idx = c << 3;
  int b = idx >> 10;          // row
  int k = idx & 1023;         // col
  const float* src = (k < 512) ? (x + (size_t)b * 512 + k)
                               : (h + (size_t)b * 512 + (k - 512));
  float4 lo = ((const float4*)src)[0];
  float4 hi = ((const float4*)src)[1];
  union { unsigned short s[8]; uint4 u; } o;
  o.s[0]=f2bf(lo.x); o.s[1]=f2bf(lo.y); o.s[2]=f2bf(lo.z); o.s[3]=f2bf(lo.w);
  o.s[4]=f2bf(hi.x); o.s[5]=f2bf(hi.y); o.s[6]=f2bf(hi.z); o.s[7]=f2bf(hi.w);
  ((uint4*)A)[c] = o.u;
}

struct GatePtrs {
  const float* wx[4];  // gate order: i, g, f, o
  const float* wh[4];
  const float* bx[4];
  const float* bh[4];
};

// W row-major bf16 [2048][1024], rows packed r = b*128 + wn*64 + gate*16 + jl,
// j = b*32 + wn*16 + jl.
__global__ __launch_bounds__(256) void pack_w(GatePtrs P,
                                              unsigned short* __restrict__ W,
                                              float* __restrict__ bias) {
  int c = blockIdx.x * 256 + threadIdx.x;   // chunk of 8, 128 chunks per row
  int r = c >> 7;
  int k = (c & 127) << 3;
  int b    = r >> 7;
  int rem  = r & 127;
  int wn   = (rem >> 6) & 1;
  int gate = (rem >> 4) & 3;
  int jl   = rem & 15;
  int j = b * 32 + wn * 16 + jl;
  const float* src = (k < 512) ? (P.wx[gate] + (size_t)j * 512 + k)
                               : (P.wh[gate] + (size_t)j * 512 + (k - 512));
  float4 lo = ((const float4*)src)[0];
  float4 hi = ((const float4*)src)[1];
  union { unsigned short s[8]; uint4 u; } o;
  o.s[0]=f2bf(lo.x); o.s[1]=f2bf(lo.y); o.s[2]=f2bf(lo.z); o.s[3]=f2bf(lo.w);
  o.s[4]=f2bf(hi.x); o.s[5]=f2bf(hi.y); o.s[6]=f2bf(hi.z); o.s[7]=f2bf(hi.w);
  ((uint4*)W)[c] = o.u;
  if ((c & 127) == 0) bias[r] = P.bx[gate][j] + P.bh[gate][j];
}

// ---------------- fused GEMM + LSTM epilogue ----------------

__global__ __launch_bounds__(512, 2) void lstm_gemm(
    const unsigned short* __restrict__ A,    // [16384,1024] bf16 row-major
    const unsigned short* __restrict__ W,    // [2048,1024] bf16 packed rows
    const float* __restrict__ bias,          // [2048] packed
    const float* __restrict__ Cin,           // [16384,512]
    float* __restrict__ Hout,                // [16384,512]
    float* __restrict__ Cout) {              // [16384,512]
  // 2 buffers x { Akc0, Akc1, Bkc0, Bkc1 } regions, each [256 rows][32 cols]
  // bf16 = 8192 ushorts = 16 KB. Total 128 KB -> 1 block/CU.
  __shared__ __align__(16) unsigned short lds[2 * 32768];

  const int tid  = threadIdx.x;
  const int lane = tid & 63;
  const int wv   = tid >> 6;     // 0..7
  const int wm   = wv >> 2;      // 0..1 (wave row; 2 x 128 = 256)
  const int wn   = wv & 3;       // 0..3 (wave col; 4 x 64  = 256)

  // XCD-aware swizzle: 512 blocks, nwg%8==0 -> simple swizzle bijective.
  const int lin = blockIdx.x;    // 0..511
  const int xcd = lin & 7;
  const int idx = lin >> 3;
  const int bn  = idx & 7;       // 0..7
  const int bm  = (idx >> 3) * 8 + xcd;  // 0..63

  // ---- staging addressing: one region = 2 gload_lds16 per thread ----
  // T2 write side: LDS dest linear (lane*16); global source column carries
  // the involution: lane (srow, sl) fetches k-chunk sl ^ ((srow>>1)&3).
  // Rows srow and srow+16 share the same swizzle ((r+16)>>1 ≡ r>>1 mod 4).
  const int srow = lane >> 2;            // 0..15
  const int scol = (((lane & 3) ^ ((srow >> 1) & 3)) << 3);  // ushort offset
  const unsigned short* gA = A + (size_t)(bm * 256 + wv * 32 + srow) * KDIM + scol;
  const unsigned short* gB = W + (size_t)(bn * 256 + wv * 32 + srow) * KDIM + scol;
  const int lA = wv * 1024;              // wave's 32-row slab (ushorts) in a region

#define REG_A(b, c) ((b) * 32768 + (c) * 8192)
#define REG_B(b, c) ((b) * 32768 + 16384 + (c) * 8192)

#define STAGE_A(b, c, tt) do {                                      \
    const unsigned short* s_ = gA + (tt) * 64 + (c) * 32;           \
    gload_lds16(s_,            &lds[REG_A(b, c) + lA]);             \
    gload_lds16(s_ + 16 * KDIM, &lds[REG_A(b, c) + lA + 512]);      \
  } while (0)
#define STAGE_B(b, c, tt) do {                                      \
    const unsigned short* s_ = gB + (tt) * 64 + (c) * 32;           \
    gload_lds16(s_,            &lds[REG_B(b, c) + lA]);             \
    gload_lds16(s_ + 16 * KDIM, &lds[REG_B(b, c) + lA + 512]);      \
  } while (0)

  // ---- fragment addressing ----
  // T2 read side: lane (lrow, s=lane>>4) reads LDS slot s ^ ((lrow>>1)&3);
  // slot content is chunk slot^c(row) -> involution cancels, lane gets its
  // MFMA-required k-chunk. Per 16-lane group: 2 lanes/bank = conflict-free.
  const int lrow = lane & 15;
  const int kg   = (((lane >> 4) ^ ((lrow >> 1) & 3)) << 3);  // ushort offset
  const int aoff = wm * 4096 + lrow * 32 + kg;   // + h*2048 + mi*512
  const int boff = wn * 2048 + lrow * 32 + kg;   // + ni*512

  f32x4 acc[8][4] = {};   // [m: h*4+mi][gate ni]
  bf16x8 af[4], bfr[4];

#define LOAD_AF(b, c, h) do {                                                  \
    _Pragma("unroll")                                                          \
    for (int mi = 0; mi < 4; ++mi)                                             \
      af[mi] = *reinterpret_cast<const bf16x8*>(                               \
          &lds[REG_A(b, c) + aoff + (h) * 2048 + mi * 512]);                   \
  } while (0)
#define LOAD_BF(b, c) do {                                                     \
    _Pragma("unroll")                                                          \
    for (int ni = 0; ni < 4; ++ni)                                             \
      bfr[ni] = *reinterpret_cast<const bf16x8*>(                              \
          &lds[REG_B(b, c) + boff + ni * 512]);                                \
  } while (0)
#define MFMA_BLK(h) do {                                                       \
    __builtin_amdgcn_s_setprio(1);                                             \
    _Pragma("unroll")                                                          \
    for (int mi = 0; mi < 4; ++mi)                                             \
      _Pragma("unroll")                                                        \
      for (int ni = 0; ni < 4; ++ni)                                           \
        acc[(h) * 4 + mi][ni] = __builtin_amdgcn_mfma_f32_16x16x32_bf16(       \
            af[mi], bfr[ni], acc[(h) * 4 + mi][ni], 0, 0, 0);                  \
    __builtin_amdgcn_s_setprio(0);                                             \
  } while (0)

#define BAR()  __builtin_amdgcn_s_barrier()
#define SCB()  __builtin_amdgcn_sched_barrier(0)
// drain own ds_reads BEFORE the barrier -> barrier-exit implies all waves'
// reads of the previous regions are complete (single-barrier WAR safety).
#define WAIT_LGKM0() asm volatile("s_waitcnt lgkmcnt(0)" ::: "memory")

  // ---- prologue: issue order defines vmcnt arithmetic ----
  // [Bkc0(0), Akc0(0), Bkc1(0), Akc1(0), Bkc0(1), Akc0(1), Bkc1(1)]
  STAGE_B(0, 0, 0); STAGE_A(0, 0, 0); STAGE_B(0, 1, 0); STAGE_A(0, 1, 0);
  STAGE_B(1, 0, 1); STAGE_A(1, 0, 1); STAGE_B(1, 1, 1);
  asm volatile("s_waitcnt vmcnt(6)" ::: "memory");
  BAR(); SCB();

#pragma unroll 2
  for (int t = 0; t < NT; ++t) {
    const int cur = t & 1;
    const int nxt = cur ^ 1;
    const int t1 = (t + 1 < NT) ? t + 1 : NT - 1;  // clamp: redundant re-stage,
    const int t2 = (t + 2 < NT) ? t + 2 : NT - 1;  // keeps vmcnt counts uniform
    // ---- ph0: kc0, m-half 0 ----
    LOAD_AF(cur, 0, 0); LOAD_BF(cur, 0);
    STAGE_A(nxt, 1, t1);           // buf[nxt].Akc1: last read t-1.ph3, BAR'd
    WAIT_LGKM0();
    BAR(); SCB();
    MFMA_BLK(0);
    // ---- ph1: kc0, m-half 1 (bfr reused from ph0) ----
    LOAD_AF(cur, 0, 1);
    STAGE_B(cur, 0, t2);           // overwrites Bkc0(cur): drained pre ph0-BAR
    WAIT_LGKM0();
    BAR(); SCB();
    MFMA_BLK(1);
    // ---- ph2: kc1, m-half 0 ----
    LOAD_AF(cur, 1, 0); LOAD_BF(cur, 1);
    STAGE_A(cur, 0, t2);           // overwrites Akc0(cur): drained pre ph1-BAR
    WAIT_LGKM0();
    BAR(); SCB();
    MFMA_BLK(0);
    // ---- ph3: kc1, m-half 1 ----
    LOAD_AF(cur, 1, 1);
    STAGE_B(cur, 1, t2);           // overwrites Bkc1(cur): drained pre ph2-BAR
    WAIT_LGKM0();
    // counted wait: newest 3 regions (tile t+2 partial) may stay in flight;
    // everything through Akc1(t+1) complete -> tile t+1 resident.
    asm volatile("s_waitcnt vmcnt(6)" ::: "memory");
    BAR(); SCB();
    MFMA_BLK(1);
  }
  asm volatile("s_waitcnt vmcnt(0)" ::: "memory");  // drain tail stages

  // ---- epilogue: ni == gate (0=i,1=g,2=f,3=o); lane's j fixed ----
  // W-packed row = bn*256 + wn*64 + ni*16 + jl decodes (pack_w layout) to
  // j = (bn*2 + (wn>>1))*32 + (wn&1)*16 + jl, gate = ni.
  const int jl = lane & 15;
  const int rq = (lane >> 4) << 2;
  const int j  = (bn * 2 + (wn >> 1)) * 32 + (wn & 1) * 16 + jl;
  float bv[4];
#pragma unroll
  for (int ni = 0; ni < 4; ++ni)
    bv[ni] = bias[bn * 256 + wn * 64 + ni * 16 + jl];

#pragma unroll
  for (int mi = 0; mi < 8; ++mi) {
    const int row0 = bm * 256 + wm * 128 + (mi >> 2) * 64 + (mi & 3) * 16 + rq;
#pragma unroll
    for (int r = 0; r < 4; ++r) {
      int row = row0 + r;
      float iv = fast_sigmoid(acc[mi][0][r] + bv[0]);
      float gv = fast_tanh   (acc[mi][1][r] + bv[1]);
      float fv = fast_sigmoid(acc[mi][2][r] + bv[2]);
      float ov = fast_sigmoid(acc[mi][3][r] + bv[3]);
      float cold = Cin[(size_t)row * HIDN + j];
      float cnew = fv * cold + iv * gv;
      Hout[(size_t)row * HIDN + j] = ov * fast_tanh(cnew);
      Cout[(size_t)row * HIDN + j] = cnew;
    }
  }
}

// ---------------- launch ----------------

extern "C" void kernel_launch(void* const* d_in, const int* in_sizes, int n_in,
                              void* d_out, int out_size, void* d_ws, size_t ws_size,
                              hipStream_t stream) {
  const float* x   = (const float*)d_in[0];
  const float* h   = (const float*)d_in[1];
  const float* c   = (const float*)d_in[2];
  const float* Wxi = (const float*)d_in[3];  const float* bxi = (const float*)d_in[4];
  const float* Wxo = (const float*)d_in[5];  const float* bxo = (const float*)d_in[6];
  const float* Wxf = (const float*)d_in[7];  const float* bxf = (const float*)d_in[8];
  const float* Wxg = (const float*)d_in[9];  const float* bxg = (const float*)d_in[10];
  const float* Whi = (const float*)d_in[11]; const float* bhi = (const float*)d_in[12];
  const float* Who = (const float*)d_in[13]; const float* bho = (const float*)d_in[14];
  const float* Whf = (const float*)d_in[15]; const float* bhf = (const float*)d_in[16];
  const float* Whg = (const float*)d_in[17]; const float* bhg = (const float*)d_in[18];

  char* ws = (char*)d_ws;
  unsigned short* Apack = (unsigned short*)ws;                              // 32 MB
  unsigned short* Wpack = (unsigned short*)(ws + (size_t)BATCH * KDIM * 2); // 4 MB
  float* biasp = (float*)(ws + (size_t)BATCH * KDIM * 2 + (size_t)NPK * KDIM * 2);

  pack_a<<<(BATCH * KDIM / 8) / 256, 256, 0, stream>>>(x, h, Apack);

  GatePtrs P;
  P.wx[0] = Wxi; P.wx[1] = Wxg; P.wx[2] = Wxf; P.wx[3] = Wxo;
  P.wh[0] = Whi; P.wh[1] = Whg; P.wh[2] = Whf; P.wh[3] = Who;
  P.bx[0] = bxi; P.bx[1] = bxg; P.bx[2] = bxf; P.bx[3] = bxo;
  P.bh[0] = bhi; P.bh[1] = bhg; P.bh[2] = bhf; P.bh[3] = bho;
  pack_w<<<(NPK * KDIM / 8) / 256, 256, 0, stream>>>(P, Wpack, biasp);

  float* Hout = (float*)d_out;
  float* Cout = Hout + (size_t)BATCH * HIDN;
  lstm_gemm<<<dim3((BATCH / BM) * (NPK / BN)), 512, 0, stream>>>(
      Apack, Wpack, biasp, c, Hout, Cout);
}

// Round 7
// 248.110 us; speedup vs baseline: 1.0162x; 1.0075x over previous
//
#include <hip/hip_runtime.h>
#include <cstdint>
#include <cstddef>

// LSTM cell: B=16384, IN=HID=512.
// R11 = R10 swizzle + m201 phase ordering (the 2x2 completion):
//   R8:  post-BAR lgkm0 + bank conflicts      -> 29% MfmaUtil
//   R9:  pre-BAR lgkm0  + bank conflicts      -> 30%
//   R10: pre-BAR lgkm0  + swizzle (0 confl.)  -> 33%  <- drain||MFMA never overlap
//   R11: post-BAR lgkm0 + swizzle             -> predicted ~50%+ (m201: 62%)
// Phase = [reads, stage, BAR1, lgkm0+SCB, MFMA, BAR2]: waves join BAR1 with
// reads in flight; each then waits only its OWN lgkm -> drains stagger and
// overlap peers' MFMA on the same SIMD (m114 ping-pong). BAR2 (post-MFMA)
// provides WAR safety: all waves passed lgkm0 (reads done) before any wave
// issues the next phase's overwriting stage. vmcnt(6) once per tile at ph3.
// T2 swizzle unchanged from R10 (verified: SQ_LDS_BANK_CONFLICT = 0).

#define BATCH 16384
#define KDIM  1024
#define NPK   2048
#define HIDN  512

#define BM 256
#define BN 256
#define BK 64
#define NT (KDIM / BK)   // 16

typedef __bf16 bf16x8 __attribute__((ext_vector_type(8)));
typedef float  f32x4  __attribute__((ext_vector_type(4)));

__device__ __forceinline__ unsigned short f2bf(float f) {
  unsigned int u = __builtin_bit_cast(unsigned int, f);
  u += 0x7fffu + ((u >> 16) & 1u);   // RNE
  return (unsigned short)(u >> 16);
}

__device__ __forceinline__ float fast_sigmoid(float x) {
  return __builtin_amdgcn_rcpf(1.0f + __expf(-x));
}
__device__ __forceinline__ float fast_tanh(float x) {
  return 1.0f - 2.0f * __builtin_amdgcn_rcpf(1.0f + __expf(2.0f * x));
}

// async global->LDS, 16 B per lane; LDS dest = wave-uniform base + lane*16
__device__ __forceinline__ void gload_lds16(const void* gp, void* lds_wave_base) {
  auto g = (const __attribute__((address_space(1))) unsigned int*)(unsigned long long)gp;
  auto l = (__attribute__((address_space(3))) unsigned int*)
           (unsigned int)(unsigned long long)lds_wave_base;
  __builtin_amdgcn_global_load_lds(g, l, 16, 0, 0);
}

// ---------------- prep kernels (unchanged) ----------------
__global__ __launch_bounds__(256) void pack_a(const float* __restrict__ x,
                                              const float* __restrict__ h,
                                              unsigned short* __restrict__ A) {
  int c = blockIdx.x * 256 + threadIdx.x;   // chunk of 8 elements
  int idx = c << 3;
  int b = idx >> 10;          // row
  int k = idx & 1023;         // col
  const float* src = (k < 512) ? (x + (size_t)b * 512 + k)
                               : (h + (size_t)b * 512 + (k - 512));
  float4 lo = ((const float4*)src)[0];
  float4 hi = ((const float4*)src)[1];
  union { unsigned short s[8]; uint4 u; } o;
  o.s[0]=f2bf(lo.x); o.s[1]=f2bf(lo.y); o.s[2]=f2bf(lo.z); o.s[3]=f2bf(lo.w);
  o.s[4]=f2bf(hi.x); o.s[5]=f2bf(hi.y); o.s[6]=f2bf(hi.z); o.s[7]=f2bf(hi.w);
  ((uint4*)A)[c] = o.u;
}

struct GatePtrs {
  const float* wx[4];  // gate order: i, g, f, o
  const float* wh[4];
  const float* bx[4];
  const float* bh[4];
};

// W row-major bf16 [2048][1024], rows packed r = b*128 + wn*64 + gate*16 + jl,
// j = b*32 + wn*16 + jl.
__global__ __launch_bounds__(256) void pack_w(GatePtrs P,
                                              unsigned short* __restrict__ W,
                                              float* __restrict__ bias) {
  int c = blockIdx.x * 256 + threadIdx.x;   // chunk of 8, 128 chunks per row
  int r = c >> 7;
  int k = (c & 127) << 3;
  int b    = r >> 7;
  int rem  = r & 127;
  int wn   = (rem >> 6) & 1;
  int gate = (rem >> 4) & 3;
  int jl   = rem & 15;
  int j = b * 32 + wn * 16 + jl;
  const float* src = (k < 512) ? (P.wx[gate] + (size_t)j * 512 + k)
                               : (P.wh[gate] + (size_t)j * 512 + (k - 512));
  float4 lo = ((const float4*)src)[0];
  float4 hi = ((const float4*)src)[1];
  union { unsigned short s[8]; uint4 u; } o;
  o.s[0]=f2bf(lo.x); o.s[1]=f2bf(lo.y); o.s[2]=f2bf(lo.z); o.s[3]=f2bf(lo.w);
  o.s[4]=f2bf(hi.x); o.s[5]=f2bf(hi.y); o.s[6]=f2bf(hi.z); o.s[7]=f2bf(hi.w);
  ((uint4*)W)[c] = o.u;
  if ((c & 127) == 0) bias[r] = P.bx[gate][j] + P.bh[gate][j];
}

// ---------------- fused GEMM + LSTM epilogue ----------------

__global__ __launch_bounds__(512, 2) void lstm_gemm(
    const unsigned short* __restrict__ A,    // [16384,1024] bf16 row-major
    const unsigned short* __restrict__ W,    // [2048,1024] bf16 packed rows
    const float* __restrict__ bias,          // [2048] packed
    const float* __restrict__ Cin,           // [16384,512]
    float* __restrict__ Hout,                // [16384,512]
    float* __restrict__ Cout) {              // [16384,512]
  // 2 buffers x { Akc0, Akc1, Bkc0, Bkc1 } regions, each [256 rows][32 cols]
  // bf16 = 8192 ushorts = 16 KB. Total 128 KB -> 1 block/CU.
  __shared__ __align__(16) unsigned short lds[2 * 32768];

  const int tid  = threadIdx.x;
  const int lane = tid & 63;
  const int wv   = tid >> 6;     // 0..7
  const int wm   = wv >> 2;      // 0..1 (wave row; 2 x 128 = 256)
  const int wn   = wv & 3;       // 0..3 (wave col; 4 x 64  = 256)

  // XCD-aware swizzle: 512 blocks, nwg%8==0 -> simple swizzle bijective.
  const int lin = blockIdx.x;    // 0..511
  const int xcd = lin & 7;
  const int idx = lin >> 3;
  const int bn  = idx & 7;       // 0..7
  const int bm  = (idx >> 3) * 8 + xcd;  // 0..63

  // ---- staging addressing: one region = 2 gload_lds16 per thread ----
  // T2 write side: LDS dest linear (lane*16); global source column carries
  // the involution: lane (srow, sl) fetches k-chunk sl ^ ((srow>>1)&3).
  // Rows srow and srow+16 share the same swizzle ((r+16)>>1 ≡ r>>1 mod 4).
  const int srow = lane >> 2;            // 0..15
  const int scol = (((lane & 3) ^ ((srow >> 1) & 3)) << 3);  // ushort offset
  const unsigned short* gA = A + (size_t)(bm * 256 + wv * 32 + srow) * KDIM + scol;
  const unsigned short* gB = W + (size_t)(bn * 256 + wv * 32 + srow) * KDIM + scol;
  const int lA = wv * 1024;              // wave's 32-row slab (ushorts) in a region

#define REG_A(b, c) ((b) * 32768 + (c) * 8192)
#define REG_B(b, c) ((b) * 32768 + 16384 + (c) * 8192)

#define STAGE_A(b, c, tt) do {                                      \
    const unsigned short* s_ = gA + (tt) * 64 + (c) * 32;           \
    gload_lds16(s_,            &lds[REG_A(b, c) + lA]);             \
    gload_lds16(s_ + 16 * KDIM, &lds[REG_A(b, c) + lA + 512]);      \
  } while (0)
#define STAGE_B(b, c, tt) do {                                      \
    const unsigned short* s_ = gB + (tt) * 64 + (c) * 32;           \
    gload_lds16(s_,            &lds[REG_B(b, c) + lA]);             \
    gload_lds16(s_ + 16 * KDIM, &lds[REG_B(b, c) + lA + 512]);      \
  } while (0)

  // ---- fragment addressing ----
  // T2 read side: lane (lrow, s=lane>>4) reads LDS slot s ^ ((lrow>>1)&3);
  // slot content is chunk slot^c(row) -> involution cancels, lane gets its
  // MFMA-required k-chunk. Per 16-lane group: 2 lanes/bank = conflict-free
  // (verified R10: SQ_LDS_BANK_CONFLICT = 0).
  const int lrow = lane & 15;
  const int kg   = (((lane >> 4) ^ ((lrow >> 1) & 3)) << 3);  // ushort offset
  const int aoff = wm * 4096 + lrow * 32 + kg;   // + h*2048 + mi*512
  const int boff = wn * 2048 + lrow * 32 + kg;   // + ni*512

  f32x4 acc[8][4] = {};   // [m: h*4+mi][gate ni]
  bf16x8 af[4], bfr[4];

#define LOAD_AF(b, c, h) do {                                                  \
    _Pragma("unroll")                                                          \
    for (int mi = 0; mi < 4; ++mi)                                             \
      af[mi] = *reinterpret_cast<const bf16x8*>(                               \
          &lds[REG_A(b, c) + aoff + (h) * 2048 + mi * 512]);                   \
  } while (0)
#define LOAD_BF(b, c) do {                                                     \
    _Pragma("unroll")                                                          \
    for (int ni = 0; ni < 4; ++ni)                                             \
      bfr[ni] = *reinterpret_cast<const bf16x8*>(                              \
          &lds[REG_B(b, c) + boff + ni * 512]);                                \
  } while (0)
#define MFMA_BLK(h) do {                                                       \
    __builtin_amdgcn_s_setprio(1);                                             \
    _Pragma("unroll")                                                          \
    for (int mi = 0; mi < 4; ++mi)                                             \
      _Pragma("unroll")                                                        \
      for (int ni = 0; ni < 4; ++ni)                                           \
        acc[(h) * 4 + mi][ni] = __builtin_amdgcn_mfma_f32_16x16x32_bf16(       \
            af[mi], bfr[ni], acc[(h) * 4 + mi][ni], 0, 0, 0);                  \
    __builtin_amdgcn_s_setprio(0);                                             \
  } while (0)

#define BAR()  __builtin_amdgcn_s_barrier()
#define SCB()  __builtin_amdgcn_sched_barrier(0)
// post-BAR own-drain: overlaps peers' MFMA (rule #18: SCB pins MFMA below).
#define WAIT_LGKM0() do { asm volatile("s_waitcnt lgkmcnt(0)" ::: "memory"); SCB(); } while (0)

  // ---- prologue: issue order defines vmcnt arithmetic ----
  // [Bkc0(0), Akc0(0), Bkc1(0), Akc1(0), Bkc0(1), Akc0(1), Bkc1(1)]
  STAGE_B(0, 0, 0); STAGE_A(0, 0, 0); STAGE_B(0, 1, 0); STAGE_A(0, 1, 0);
  STAGE_B(1, 0, 1); STAGE_A(1, 0, 1); STAGE_B(1, 1, 1);
  asm volatile("s_waitcnt vmcnt(6)" ::: "memory");
  BAR(); SCB();

#pragma unroll 2
  for (int t = 0; t < NT; ++t) {
    const int cur = t & 1;
    const int nxt = cur ^ 1;
    const int t1 = (t + 1 < NT) ? t + 1 : NT - 1;  // clamp: redundant re-stage,
    const int t2 = (t + 2 < NT) ? t + 2 : NT - 1;  // keeps vmcnt counts uniform
    // ---- ph0: kc0, m-half 0 ----
    LOAD_AF(cur, 0, 0); LOAD_BF(cur, 0);
    STAGE_A(nxt, 1, t1);           // buf[nxt].Akc1: last read t-1.ph3 (BAR2'd)
    BAR(); WAIT_LGKM0();
    MFMA_BLK(0);
    BAR(); SCB();                  // all waves' Bkc0(cur) reads drained
    // ---- ph1: kc0, m-half 1 (bfr reused from ph0) ----
    LOAD_AF(cur, 0, 1);
    STAGE_B(cur, 0, t2);           // overwrites Bkc0(cur): freed at ph0 BAR2
    BAR(); WAIT_LGKM0();
    MFMA_BLK(1);
    BAR(); SCB();                  // all waves' Akc0(cur) reads drained
    // ---- ph2: kc1, m-half 0 ----
    LOAD_AF(cur, 1, 0); LOAD_BF(cur, 1);
    STAGE_A(cur, 0, t2);           // overwrites Akc0(cur): freed at ph1 BAR2
    BAR(); WAIT_LGKM0();
    MFMA_BLK(0);
    BAR(); SCB();                  // all waves' Bkc1(cur) reads drained
    // ---- ph3: kc1, m-half 1 ----
    LOAD_AF(cur, 1, 1);
    STAGE_B(cur, 1, t2);           // overwrites Bkc1(cur): freed at ph2 BAR2
    BAR(); WAIT_LGKM0();
    MFMA_BLK(1);
    // counted wait: newest 3 regions (tile t+2 partial) may stay in flight;
    // everything through Akc1(t+1) complete -> tile t+1 resident.
    asm volatile("s_waitcnt vmcnt(6)" ::: "memory");
    BAR(); SCB();                  // all waves' Akc1(cur) reads drained
  }
  asm volatile("s_waitcnt vmcnt(0)" ::: "memory");  // drain tail stages

  // ---- epilogue: ni == gate (0=i,1=g,2=f,3=o); lane's j fixed ----
  // W-packed row = bn*256 + wn*64 + ni*16 + jl decodes (pack_w layout) to
  // j = (bn*2 + (wn>>1))*32 + (wn&1)*16 + jl, gate = ni.
  const int jl = lane & 15;
  const int rq = (lane >> 4) << 2;
  const int j  = (bn * 2 + (wn >> 1)) * 32 + (wn & 1) * 16 + jl;
  float bv[4];
#pragma unroll
  for (int ni = 0; ni < 4; ++ni)
    bv[ni] = bias[bn * 256 + wn * 64 + ni * 16 + jl];

#pragma unroll
  for (int mi = 0; mi < 8; ++mi) {
    const int row0 = bm * 256 + wm * 128 + (mi >> 2) * 64 + (mi & 3) * 16 + rq;
#pragma unroll
    for (int r = 0; r < 4; ++r) {
      int row = row0 + r;
      float iv = fast_sigmoid(acc[mi][0][r] + bv[0]);
      float gv = fast_tanh   (acc[mi][1][r] + bv[1]);
      float fv = fast_sigmoid(acc[mi][2][r] + bv[2]);
      float ov = fast_sigmoid(acc[mi][3][r] + bv[3]);
      float cold = Cin[(size_t)row * HIDN + j];
      float cnew = fv * cold + iv * gv;
      Hout[(size_t)row * HIDN + j] = ov * fast_tanh(cnew);
      Cout[(size_t)row * HIDN + j] = cnew;
    }
  }
}

// ---------------- launch ----------------

extern "C" void kernel_launch(void* const* d_in, const int* in_sizes, int n_in,
                              void* d_out, int out_size, void* d_ws, size_t ws_size,
                              hipStream_t stream) {
  const float* x   = (const float*)d_in[0];
  const float* h   = (const float*)d_in[1];
  const float* c   = (const float*)d_in[2];
  const float* Wxi = (const float*)d_in[3];  const float* bxi = (const float*)d_in[4];
  const float* Wxo = (const float*)d_in[5];  const float* bxo = (const float*)d_in[6];
  const float* Wxf = (const float*)d_in[7];  const float* bxf = (const float*)d_in[8];
  const float* Wxg = (const float*)d_in[9];  const float* bxg = (const float*)d_in[10];
  const float* Whi = (const float*)d_in[11]; const float* bhi = (const float*)d_in[12];
  const float* Who = (const float*)d_in[13]; const float* bho = (const float*)d_in[14];
  const float* Whf = (const float*)d_in[15]; const float* bhf = (const float*)d_in[16];
  const float* Whg = (const float*)d_in[17]; const float* bhg = (const float*)d_in[18];

  char* ws = (char*)d_ws;
  unsigned short* Apack = (unsigned short*)ws;                              // 32 MB
  unsigned short* Wpack = (unsigned short*)(ws + (size_t)BATCH * KDIM * 2); // 4 MB
  float* biasp = (float*)(ws + (size_t)BATCH * KDIM * 2 + (size_t)NPK * KDIM * 2);

  pack_a<<<(BATCH * KDIM / 8) / 256, 256, 0, stream>>>(x, h, Apack);

  GatePtrs P;
  P.wx[0] = Wxi; P.wx[1] = Wxg; P.wx[2] = Wxf; P.wx[3] = Wxo;
  P.wh[0] = Whi; P.wh[1] = Whg; P.wh[2] = Whf; P.wh[3] = Who;
  P.bx[0] = bxi; P.bx[1] = bxg; P.bx[2] = bxf; P.bx[3] = bxo;
  P.bh[0] = bhi; P.bh[1] = bhg; P.bh[2] = bhf; P.bh[3] = bho;
  pack_w<<<(NPK * KDIM / 8) / 256, 256, 0, stream>>>(P, Wpack, biasp);

  float* Hout = (float*)d_out;
  float* Cout = Hout + (size_t)BATCH * HIDN;
  lstm_gemm<<<dim3((BATCH / BM) * (NPK / BN)), 512, 0, stream>>>(
      Apack, Wpack, biasp, c, Hout, Cout);
}

// Round 8
// 245.239 us; speedup vs baseline: 1.0281x; 1.0117x over previous
//
#include <hip/hip_runtime.h>
#include <cstdint>
#include <cstddef>

// LSTM cell: B=16384, IN=HID=512.
// R13 = R10 + FRAGMENT software pipeline (counted lgkm, the missing m201
// ingredient). Evidence: R8-R11 all ~30% MfmaUtil because frag reads are
// issued+drained+consumed in the SAME phase -> LDS(576cy) and MFMA(516cy)
// alternate serially per phase (1650cy measured). Fix: issue phase p+1's
// fragments during phase p; they drain under p's MFMA+barrier; p+1's MFMA
// waits a counted lgkm (compiler-emitted) instead of a full drain.
//  - afA/afB ping-pong per phase (+16 VGPR; total ~252 <= 256, 2 waves/SIMD)
//  - bfr single set, reloaded AFTER its last-use MFMA (SCB pins order)
//  - one barrier per phase (end); reads cross barriers (m139: raw s_barrier
//    does not force drains)
//  - p3: [stage; vmcnt(6); frag-issues(t+1); MFMA; BAR] -- vmcnt(6) with
//    p3's stage already issued keeps exactly the 3 newest regions (t+2) in
//    flight and certifies ALL t+1 regions before t+1 reads issue (R10 ledger)
// T2 swizzle unchanged (R10 verified: SQ_LDS_BANK_CONFLICT = 0).

#define BATCH 16384
#define KDIM  1024
#define NPK   2048
#define HIDN  512

#define BM 256
#define BN 256
#define BK 64
#define NT (KDIM / BK)   // 16

typedef __bf16 bf16x8 __attribute__((ext_vector_type(8)));
typedef float  f32x4  __attribute__((ext_vector_type(4)));

__device__ __forceinline__ unsigned short f2bf(float f) {
  unsigned int u = __builtin_bit_cast(unsigned int, f);
  u += 0x7fffu + ((u >> 16) & 1u);   // RNE
  return (unsigned short)(u >> 16);
}

__device__ __forceinline__ float fast_sigmoid(float x) {
  return __builtin_amdgcn_rcpf(1.0f + __expf(-x));
}
__device__ __forceinline__ float fast_tanh(float x) {
  return 1.0f - 2.0f * __builtin_amdgcn_rcpf(1.0f + __expf(2.0f * x));
}

// async global->LDS, 16 B per lane; LDS dest = wave-uniform base + lane*16
__device__ __forceinline__ void gload_lds16(const void* gp, void* lds_wave_base) {
  auto g = (const __attribute__((address_space(1))) unsigned int*)(unsigned long long)gp;
  auto l = (__attribute__((address_space(3))) unsigned int*)
           (unsigned int)(unsigned long long)lds_wave_base;
  __builtin_amdgcn_global_load_lds(g, l, 16, 0, 0);
}

// ---------------- prep kernels (unchanged) ----------------
__global__ __launch_bounds__(256) void pack_a(const float* __restrict__ x,
                                              const float* __restrict__ h,
                                              unsigned short* __restrict__ A) {
  int c = blockIdx.x * 256 + threadIdx.x;   // chunk of 8 elements
  int idx = c << 3;
  int b = idx >> 10;          // row
  int k = idx & 1023;         // col
  const float* src = (k < 512) ? (x + (size_t)b * 512 + k)
                               : (h + (size_t)b * 512 + (k - 512));
  float4 lo = ((const float4*)src)[0];
  float4 hi = ((const float4*)src)[1];
  union { unsigned short s[8]; uint4 u; } o;
  o.s[0]=f2bf(lo.x); o.s[1]=f2bf(lo.y); o.s[2]=f2bf(lo.z); o.s[3]=f2bf(lo.w);
  o.s[4]=f2bf(hi.x); o.s[5]=f2bf(hi.y); o.s[6]=f2bf(hi.z); o.s[7]=f2bf(hi.w);
  ((uint4*)A)[c] = o.u;
}

struct GatePtrs {
  const float* wx[4];  // gate order: i, g, f, o
  const float* wh[4];
  const float* bx[4];
  const float* bh[4];
};

// W row-major bf16 [2048][1024], rows packed r = b*128 + wn*64 + gate*16 + jl,
// j = b*32 + wn*16 + jl.
__global__ __launch_bounds__(256) void pack_w(GatePtrs P,
                                              unsigned short* __restrict__ W,
                                              float* __restrict__ bias) {
  int c = blockIdx.x * 256 + threadIdx.x;   // chunk of 8, 128 chunks per row
  int r = c >> 7;
  int k = (c & 127) << 3;
  int b    = r >> 7;
  int rem  = r & 127;
  int wn   = (rem >> 6) & 1;
  int gate = (rem >> 4) & 3;
  int jl   = rem & 15;
  int j = b * 32 + wn * 16 + jl;
  const float* src = (k < 512) ? (P.wx[gate] + (size_t)j * 512 + k)
                               : (P.wh[gate] + (size_t)j * 512 + (k - 512));
  float4 lo = ((const float4*)src)[0];
  float4 hi = ((const float4*)src)[1];
  union { unsigned short s[8]; uint4 u; } o;
  o.s[0]=f2bf(lo.x); o.s[1]=f2bf(lo.y); o.s[2]=f2bf(lo.z); o.s[3]=f2bf(lo.w);
  o.s[4]=f2bf(hi.x); o.s[5]=f2bf(hi.y); o.s[6]=f2bf(hi.z); o.s[7]=f2bf(hi.w);
  ((uint4*)W)[c] = o.u;
  if ((c & 127) == 0) bias[r] = P.bx[gate][j] + P.bh[gate][j];
}

// ---------------- fused GEMM + LSTM epilogue ----------------

__global__ __launch_bounds__(512, 2) void lstm_gemm(
    const unsigned short* __restrict__ A,    // [16384,1024] bf16 row-major
    const unsigned short* __restrict__ W,    // [2048,1024] bf16 packed rows
    const float* __restrict__ bias,          // [2048] packed
    const float* __restrict__ Cin,           // [16384,512]
    float* __restrict__ Hout,                // [16384,512]
    float* __restrict__ Cout) {              // [16384,512]
  // 2 buffers x { Akc0, Akc1, Bkc0, Bkc1 } regions, each [256 rows][32 cols]
  // bf16 = 8192 ushorts = 16 KB. Total 128 KB -> 1 block/CU.
  __shared__ __align__(16) unsigned short lds[2 * 32768];

  const int tid  = threadIdx.x;
  const int lane = tid & 63;
  const int wv   = tid >> 6;     // 0..7
  const int wm   = wv >> 2;      // 0..1 (wave row; 2 x 128 = 256)
  const int wn   = wv & 3;       // 0..3 (wave col; 4 x 64  = 256)

  // XCD-aware swizzle: 512 blocks, nwg%8==0 -> simple swizzle bijective.
  const int lin = blockIdx.x;    // 0..511
  const int xcd = lin & 7;
  const int idx = lin >> 3;
  const int bn  = idx & 7;       // 0..7
  const int bm  = (idx >> 3) * 8 + xcd;  // 0..63

  // ---- staging addressing: one region = 2 gload_lds16 per thread ----
  // T2 write side: LDS dest linear; global source column pre-swizzled:
  // lane (srow, sl) fetches k-chunk sl ^ ((srow>>1)&3). Rows srow, srow+16
  // share the swizzle constant.
  const int srow = lane >> 2;            // 0..15
  const int scol = (((lane & 3) ^ ((srow >> 1) & 3)) << 3);  // ushort offset
  const unsigned short* gA = A + (size_t)(bm * 256 + wv * 32 + srow) * KDIM + scol;
  const unsigned short* gB = W + (size_t)(bn * 256 + wv * 32 + srow) * KDIM + scol;
  const int lA = wv * 1024;              // wave's 32-row slab (ushorts) in a region

#define REG_A(b, c) ((b) * 32768 + (c) * 8192)
#define REG_B(b, c) ((b) * 32768 + 16384 + (c) * 8192)

#define STAGE_A(b, c, tt) do {                                      \
    const unsigned short* s_ = gA + (tt) * 64 + (c) * 32;           \
    gload_lds16(s_,            &lds[REG_A(b, c) + lA]);             \
    gload_lds16(s_ + 16 * KDIM, &lds[REG_A(b, c) + lA + 512]);      \
  } while (0)
#define STAGE_B(b, c, tt) do {                                      \
    const unsigned short* s_ = gB + (tt) * 64 + (c) * 32;           \
    gload_lds16(s_,            &lds[REG_B(b, c) + lA]);             \
    gload_lds16(s_ + 16 * KDIM, &lds[REG_B(b, c) + lA + 512]);      \
  } while (0)

  // ---- fragment addressing ----
  // T2 read side: lane (lrow, s=lane>>4) reads slot s ^ ((lrow>>1)&3);
  // involution cancels -> correct k-chunk, conflict-free (R10: 0 conflicts).
  const int lrow = lane & 15;
  const int kg   = (((lane >> 4) ^ ((lrow >> 1) & 3)) << 3);  // ushort offset
  const int aoff = wm * 4096 + lrow * 32 + kg;   // + h*2048 + mi*512
  const int boff = wn * 2048 + lrow * 32 + kg;   // + ni*512

  f32x4 acc[8][4] = {};   // [m: h*4+mi][gate ni]  (AGPR file, 128 regs)
  bf16x8 afA[4], afB[4];  // ping-pong A-fragment sets (static names, rule #20)
  bf16x8 bfr[4];          // single B-fragment set, reloaded post-last-use

#define LOAD_AF_TO(dst, b, c, h) do {                                          \
    _Pragma("unroll")                                                          \
    for (int mi = 0; mi < 4; ++mi)                                             \
      dst[mi] = *reinterpret_cast<const bf16x8*>(                              \
          &lds[REG_A(b, c) + aoff + (h) * 2048 + mi * 512]);                   \
  } while (0)
#define LOAD_BF_TO(dst, b, c) do {                                             \
    _Pragma("unroll")                                                          \
    for (int ni = 0; ni < 4; ++ni)                                             \
      dst[ni] = *reinterpret_cast<const bf16x8*>(                              \
          &lds[REG_B(b, c) + boff + ni * 512]);                                \
  } while (0)
// MFMA consumes a-set + bfr; compiler emits the counted lgkmcnt before the
// cluster (operands issued one phase earlier -> drained under prior MFMA).
#define MFMA_BLK(h, aset) do {                                                 \
    __builtin_amdgcn_s_setprio(1);                                             \
    _Pragma("unroll")                                                          \
    for (int mi = 0; mi < 4; ++mi)                                             \
      _Pragma("unroll")                                                        \
      for (int ni = 0; ni < 4; ++ni)                                           \
        acc[(h) * 4 + mi][ni] = __builtin_amdgcn_mfma_f32_16x16x32_bf16(       \
            aset[mi], bfr[ni], acc[(h) * 4 + mi][ni], 0, 0, 0);                \
    __builtin_amdgcn_s_setprio(0);                                             \
  } while (0)

#define BAR()  __builtin_amdgcn_s_barrier()
#define SCB()  __builtin_amdgcn_sched_barrier(0)

  // ---- prologue ----
  // [Bkc0(0), Akc0(0), Bkc1(0), Akc1(0), Bkc0(1), Akc0(1), Bkc1(1)] = 14 loads
  // vmcnt(6) -> 3 newest regions (t=1 partial) in flight; all t=0 certified.
  STAGE_B(0, 0, 0); STAGE_A(0, 0, 0); STAGE_B(0, 1, 0); STAGE_A(0, 1, 0);
  STAGE_B(1, 0, 1); STAGE_A(1, 0, 1); STAGE_B(1, 1, 1);
  asm volatile("s_waitcnt vmcnt(6)" ::: "memory");
  BAR(); SCB();
  LOAD_AF_TO(afA, 0, 0, 0);   // frags for t=0 p0 (drain under loop entry)
  LOAD_BF_TO(bfr, 0, 0);

#pragma unroll 2
  for (int t = 0; t < NT; ++t) {
    const int cur = t & 1;
    const int nxt = cur ^ 1;
    const int t1 = (t + 1 < NT) ? t + 1 : NT - 1;  // clamp: redundant re-stage,
    const int t2 = (t + 2 < NT) ? t + 2 : NT - 1;  // keeps vmcnt counts uniform
    // ---- p0: MFMA(kc0,h0)[afA,bfr]; issue afB <- (kc0,h1) ----
    LOAD_AF_TO(afB, cur, 0, 1);
    STAGE_A(nxt, 1, t1);           // buf[nxt].Akc1: readers drained by t-1.p3 BAR
    MFMA_BLK(0, afA);
    SCB();                         // pin: no reloads above, no MFMA sink below
    BAR();                         // all waves' Bkc0/Akc0(cur) p0-operand reads done
    // ---- p1: MFMA(kc0,h1)[afB,bfr]; issue afA <- (kc1,h0); reload bfr <- kc1 ----
    LOAD_AF_TO(afA, cur, 1, 0);
    STAGE_B(cur, 0, t2);           // overwrites Bkc0(cur): reads drained pre p0-BAR
    MFMA_BLK(1, afB);
    SCB();                         // bfr reload must stay below its last use
    LOAD_BF_TO(bfr, cur, 1);
    BAR();
    // ---- p2: MFMA(kc1,h0)[afA,bfr]; issue afB <- (kc1,h1) ----
    LOAD_AF_TO(afB, cur, 1, 1);
    STAGE_A(cur, 0, t2);           // overwrites Akc0(cur): drained pre p1-BAR
    MFMA_BLK(0, afA);
    SCB();
    BAR();
    // ---- p3: stage; vmcnt(6); issue t+1 frags; MFMA(kc1,h1)[afB,bfr] ----
    STAGE_B(cur, 1, t2);           // overwrites Bkc1(cur): drained pre p2-BAR
    // 14 loads outstanding; keep newest 6 = {p1,p2,p3 stages}(t+2);
    // certifies Akc1(t+1) (p0 stage) and everything older -> t+1 resident.
    asm volatile("s_waitcnt vmcnt(6)" ::: "memory");
    if (t < NT - 1) LOAD_AF_TO(afA, nxt, 0, 0);   // frags for t+1 p0
    MFMA_BLK(1, afB);
    SCB();
    if (t < NT - 1) LOAD_BF_TO(bfr, nxt, 0);      // after bfr's last use (kc1)
    BAR();
  }
  asm volatile("s_waitcnt vmcnt(0)" ::: "memory");  // drain tail stages

  // ---- epilogue: ni == gate (0=i,1=g,2=f,3=o); lane's j fixed ----
  // W-packed row = bn*256 + wn*64 + ni*16 + jl decodes (pack_w layout) to
  // j = (bn*2 + (wn>>1))*32 + (wn&1)*16 + jl, gate = ni.
  const int jl = lane & 15;
  const int rq = (lane >> 4) << 2;
  const int j  = (bn * 2 + (wn >> 1)) * 32 + (wn & 1) * 16 + jl;
  float bv[4];
#pragma unroll
  for (int ni = 0; ni < 4; ++ni)
    bv[ni] = bias[bn * 256 + wn * 64 + ni * 16 + jl];

#pragma unroll
  for (int mi = 0; mi < 8; ++mi) {
    const int row0 = bm * 256 + wm * 128 + (mi >> 2) * 64 + (mi & 3) * 16 + rq;
#pragma unroll
    for (int r = 0; r < 4; ++r) {
      int row = row0 + r;
      float iv = fast_sigmoid(acc[mi][0][r] + bv[0]);
      float gv = fast_tanh   (acc[mi][1][r] + bv[1]);
      float fv = fast_sigmoid(acc[mi][2][r] + bv[2]);
      float ov = fast_sigmoid(acc[mi][3][r] + bv[3]);
      float cold = Cin[(size_t)row * HIDN + j];
      float cnew = fv * cold + iv * gv;
      Hout[(size_t)row * HIDN + j] = ov * fast_tanh(cnew);
      Cout[(size_t)row * HIDN + j] = cnew;
    }
  }
}

// ---------------- launch ----------------

extern "C" void kernel_launch(void* const* d_in, const int* in_sizes, int n_in,
                              void* d_out, int out_size, void* d_ws, size_t ws_size,
                              hipStream_t stream) {
  const float* x   = (const float*)d_in[0];
  const float* h   = (const float*)d_in[1];
  const float* c   = (const float*)d_in[2];
  const float* Wxi = (const float*)d_in[3];  const float* bxi = (const float*)d_in[4];
  const float* Wxo = (const float*)d_in[5];  const float* bxo = (const float*)d_in[6];
  const float* Wxf = (const float*)d_in[7];  const float* bxf = (const float*)d_in[8];
  const float* Wxg = (const float*)d_in[9];  const float* bxg = (const float*)d_in[10];
  const float* Whi = (const float*)d_in[11]; const float* bhi = (const float*)d_in[12];
  const float* Who = (const float*)d_in[13]; const float* bho = (const float*)d_in[14];
  const float* Whf = (const float*)d_in[15]; const float* bhf = (const float*)d_in[16];
  const float* Whg = (const float*)d_in[17]; const float* bhg = (const float*)d_in[18];

  char* ws = (char*)d_ws;
  unsigned short* Apack = (unsigned short*)ws;                              // 32 MB
  unsigned short* Wpack = (unsigned short*)(ws + (size_t)BATCH * KDIM * 2); // 4 MB
  float* biasp = (float*)(ws + (size_t)BATCH * KDIM * 2 + (size_t)NPK * KDIM * 2);

  pack_a<<<(BATCH * KDIM / 8) / 256, 256, 0, stream>>>(x, h, Apack);

  GatePtrs P;
  P.wx[0] = Wxi; P.wx[1] = Wxg; P.wx[2] = Wxf; P.wx[3] = Wxo;
  P.wh[0] = Whi; P.wh[1] = Whg; P.wh[2] = Whf; P.wh[3] = Who;
  P.bx[0] = bxi; P.bx[1] = bxg; P.bx[2] = bxf; P.bx[3] = bxo;
  P.bh[0] = bhi; P.bh[1] = bhg; P.bh[2] = bhf; P.bh[3] = bho;
  pack_w<<<(NPK * KDIM / 8) / 256, 256, 0, stream>>>(P, Wpack, biasp);

  float* Hout = (float*)d_out;
  float* Cout = Hout + (size_t)BATCH * HIDN;
  lstm_gemm<<<dim3((BATCH / BM) * (NPK / BN)), 512, 0, stream>>>(
      Apack, Wpack, biasp, c, Hout, Cout);
}